// Round 2
// baseline (1228.350 us; speedup 1.0000x reference)
//
#include <hip/hip_runtime.h>
#include <math.h>

// Fused Embedder MLP: 4 ->128 ->256 ->128 ->512, exact GELU, + emb[token],
// pad rows -> emb[0]. Layers 2-4 mfma_f32_16x16x32_bf16, weights pre-swizzled
// into B-frag layout in d_ws. 32 rows/wave, 128 rows/block.
// R2: k-split layer3 -> 8 KiB LDS/wave (32 KiB/block, 4-5 blocks/CU vs 2),
// no __syncthreads (wave-private LDS slices, in-order DS pipe +
// wave_barrier for compiler ordering), vectorized epilogue (LDS-staged
// float4 stores + float4 emb gathers), __launch_bounds__(256,4).

typedef float  f32x4  __attribute__((ext_vector_type(4)));
typedef short  s16x8  __attribute__((ext_vector_type(8)));
typedef __bf16 bf16x8 __attribute__((ext_vector_type(8)));

__device__ __forceinline__ unsigned short f2bf(float x) {
  unsigned u = __builtin_bit_cast(unsigned, x);
  u = (u + 0x7FFFu + ((u >> 16) & 1u)) >> 16;   // RNE
  return (unsigned short)u;
}
__device__ __forceinline__ float gelu_exact(float x) {
  return 0.5f * x * (1.0f + erff(x * 0.70710678118654752f));
}
#define WAVE_FENCE() __builtin_amdgcn_wave_barrier()

// ---------------- prep: W2/W3/W4 fp32 -> bf16 B-fragments in ws ----------------
// Frag f=(nn*KT+kk): element j of lane L is B[k=kk*32+(L>>4)*8+j][n=nn*16+(L&15)]
__global__ void embed_prep(const float* __restrict__ W2, const float* __restrict__ W3,
                           const float* __restrict__ W4, short* __restrict__ ws) {
  int tid = blockIdx.x * 256 + threadIdx.x;         // 16384 threads total
  const float* W; int K; int base; int e;
  if (tid < 4096)      { W = W2; K = 128; base = 0;     e = tid; }        // 256x128
  else if (tid < 8192) { W = W3; K = 256; base = 32768; e = tid - 4096; } // 128x256
  else                 { W = W4; K = 128; base = 65536; e = tid - 8192; } // 512x128
  int lane = e & 63, f = e >> 6;
  int kt = K >> 5;
  int nn = f / kt, kk = f - nn * kt;
  int n  = nn * 16 + (lane & 15);
  int k0 = kk * 32 + (lane >> 4) * 8;
  const float* src = W + n * K + k0;
  s16x8 v;
#pragma unroll
  for (int j = 0; j < 8; j++) v[j] = (short)f2bf(src[j]);
  *reinterpret_cast<s16x8*>(ws + base + e * 8) = v;
}

// ---------------- main fused kernel ----------------
__global__ __launch_bounds__(256, 4) void embed_main(
    const float* __restrict__ jinfo, const int* __restrict__ jtok,
    const float* __restrict__ emb,   const float* __restrict__ W1,
    const float* __restrict__ b1,    const float* __restrict__ b2,
    const float* __restrict__ b3,    const short* __restrict__ wsW,
    float* __restrict__ out) {
  __shared__ short lds_raw[4][4096];   // 8 KiB per wave (wave-private slice)
  const int lane = threadIdx.x & 63;
  const int wave = threadIdx.x >> 6;
  const int q = lane >> 4, c = lane & 15;
  const int rowBase = blockIdx.x * 128 + wave * 32;
  short* S  = lds_raw[wave];                      // bf16 act buffer: 32x128 XOR-swizzled
  float* SF = reinterpret_cast<float*>(S);        // f32 out-stage:   32x64  XOR-swizzled

  const float4* jp = reinterpret_cast<const float4*>(jinfo);

  // ---- layer 1: [4->128] VALU, emit A-frags (A[m=lane&15][k=q*8+j]) ----
  float4 x0 = jp[rowBase + c];
  float4 x1 = jp[rowBase + 16 + c];
  s16x8 a2s[2][4];
#pragma unroll
  for (int kk = 0; kk < 4; kk++) {
#pragma unroll
    for (int j = 0; j < 8; j++) {
      int f = kk * 32 + q * 8 + j;
      float4 w = reinterpret_cast<const float4*>(W1)[f];
      float bb = b1[f];
      float h0 = fmaf(w.x, x0.x, fmaf(w.y, x0.y, fmaf(w.z, x0.z, fmaf(w.w, x0.w, bb))));
      float h1 = fmaf(w.x, x1.x, fmaf(w.y, x1.y, fmaf(w.z, x1.z, fmaf(w.w, x1.w, bb))));
      a2s[0][kk][j] = (short)f2bf(gelu_exact(h0));
      a2s[1][kk][j] = (short)f2bf(gelu_exact(h1));
    }
  }

  const s16x8* fr2 = reinterpret_cast<const s16x8*>(wsW);          // 16 nn x 4 kk
  const s16x8* fr3 = reinterpret_cast<const s16x8*>(wsW + 32768);  //  8 nn x 8 kk
  const s16x8* fr4 = reinterpret_cast<const s16x8*>(wsW + 65536);  // 32 nn x 4 kk

  // ---- layers 2+3 fused, k-split: per half h, compute H2[:,128h:128h+128]
  // into LDS, then accumulate layer3 partial over that k-half. acc3 stays
  // in registers across halves (2 tiles x 8 nn x 4 = 64 VGPRs).
  f32x4 acc3[2][8];
#pragma unroll
  for (int t = 0; t < 2; t++)
#pragma unroll
    for (int nn = 0; nn < 8; nn++) acc3[t][nn] = (f32x4){0.f, 0.f, 0.f, 0.f};

  for (int h = 0; h < 2; h++) {
    // layer 2 half: nn_global = h*8 + nn8
#pragma unroll
    for (int nn8 = 0; nn8 < 8; nn8++) {
      f32x4 ac0 = {0.f, 0.f, 0.f, 0.f}, ac1 = {0.f, 0.f, 0.f, 0.f};
#pragma unroll
      for (int kk = 0; kk < 4; kk++) {
        bf16x8 bfr = __builtin_bit_cast(bf16x8, fr2[((h * 8 + nn8) * 4 + kk) * 64 + lane]);
        ac0 = __builtin_amdgcn_mfma_f32_16x16x32_bf16(__builtin_bit_cast(bf16x8, a2s[0][kk]), bfr, ac0, 0, 0, 0);
        ac1 = __builtin_amdgcn_mfma_f32_16x16x32_bf16(__builtin_bit_cast(bf16x8, a2s[1][kk]), bfr, ac1, 0, 0, 0);
      }
      float bias = b2[(h * 8 + nn8) * 16 + c];
      int g = nn8 * 2 + (c >> 3), w = c & 7;
#pragma unroll
      for (int t = 0; t < 2; t++) {
        f32x4 av = t ? ac1 : ac0;
#pragma unroll
        for (int r = 0; r < 4; r++) {
          int m = t * 16 + q * 4 + r;   // D-layout: row=(lane>>4)*4+r, col=lane&15
          S[m * 128 + (((g ^ m) & 15) << 3) + w] = (short)f2bf(gelu_exact(av[r] + bias));
        }
      }
    }
    WAVE_FENCE();
    // layer 3 partial: A-frags from this H2 half (local cols 0..127)
    s16x8 a3[2][4];
#pragma unroll
    for (int t = 0; t < 2; t++)
#pragma unroll
      for (int kkl = 0; kkl < 4; kkl++) {
        int m = t * 16 + c;
        int g = kkl * 4 + q;
        a3[t][kkl] = *reinterpret_cast<const s16x8*>(&S[m * 128 + (((g ^ m) & 15) << 3)]);
      }
    WAVE_FENCE();
#pragma unroll
    for (int nn = 0; nn < 8; nn++)
#pragma unroll
      for (int kkl = 0; kkl < 4; kkl++) {
        bf16x8 bfr = __builtin_bit_cast(bf16x8, fr3[(nn * 8 + h * 4 + kkl) * 64 + lane]);
        acc3[0][nn] = __builtin_amdgcn_mfma_f32_16x16x32_bf16(__builtin_bit_cast(bf16x8, a3[0][kkl]), bfr, acc3[0][nn], 0, 0, 0);
        acc3[1][nn] = __builtin_amdgcn_mfma_f32_16x16x32_bf16(__builtin_bit_cast(bf16x8, a3[1][kkl]), bfr, acc3[1][nn], 0, 0, 0);
      }
    WAVE_FENCE();
  }

  // ---- layer 3 epilogue: bias+gelu -> H3 (32x128) into LDS ----
#pragma unroll
  for (int nn = 0; nn < 8; nn++) {
    float bias = b3[nn * 16 + c];
    int g = nn * 2 + (c >> 3), w = c & 7;
#pragma unroll
    for (int t = 0; t < 2; t++)
#pragma unroll
      for (int r = 0; r < 4; r++) {
        int m = t * 16 + q * 4 + r;
        S[m * 128 + (((g ^ m) & 15) << 3) + w] = (short)f2bf(gelu_exact(acc3[t][nn][r] + bias));
      }
  }
  WAVE_FENCE();
  // A-frags of H3 (held in regs through layer 4; LDS is reused for out-stage)
  s16x8 a4[2][4];
#pragma unroll
  for (int t = 0; t < 2; t++)
#pragma unroll
    for (int kk = 0; kk < 4; kk++) {
      int m = t * 16 + c;
      int g = kk * 4 + q;
      a4[t][kk] = *reinterpret_cast<const s16x8*>(&S[m * 128 + (((g ^ m) & 15) << 3)]);
    }
  WAVE_FENCE();

  // ---- pad mask + token per lane-row (row_local = 4*i + (lane>>4)) ----
  int   offE[8];
  float mul[8];
#pragma unroll
  for (int i = 0; i < 8; i++) {
    int row = rowBase + 4 * i + (lane >> 4);
    float4 x = jp[row];
    bool pad = (x.x == 0.f) && (x.y == 0.f) && (x.z == 0.f) && (x.w == 0.f);
    int tok = jtok[row];
    offE[i] = (pad ? 0 : tok) * 512;
    mul[i]  = pad ? 0.f : 1.f;
  }

  // ---- layer 4: [128->512] in 8 groups of 64 cols; stage each 32x64 f32
  // tile through LDS (XOR-swizzled) -> float4 emb gather + float4 store ----
#pragma unroll
  for (int g4 = 0; g4 < 8; g4++) {
    f32x4 acc4[2][4];
#pragma unroll
    for (int t = 0; t < 2; t++)
#pragma unroll
      for (int n2 = 0; n2 < 4; n2++) acc4[t][n2] = (f32x4){0.f, 0.f, 0.f, 0.f};
#pragma unroll
    for (int n2 = 0; n2 < 4; n2++)
#pragma unroll
      for (int kk = 0; kk < 4; kk++) {
        bf16x8 bfr = __builtin_bit_cast(bf16x8, fr4[((g4 * 4 + n2) * 4 + kk) * 64 + lane]);
        acc4[0][n2] = __builtin_amdgcn_mfma_f32_16x16x32_bf16(__builtin_bit_cast(bf16x8, a4[0][kk]), bfr, acc4[0][n2], 0, 0, 0);
        acc4[1][n2] = __builtin_amdgcn_mfma_f32_16x16x32_bf16(__builtin_bit_cast(bf16x8, a4[1][kk]), bfr, acc4[1][n2], 0, 0, 0);
      }
    WAVE_FENCE();
    // scatter D-layout -> 32x64 f32 tile, XOR-swizzled row-major (2-way, free)
#pragma unroll
    for (int n2 = 0; n2 < 4; n2++) {
      int colL = n2 * 16 + c;
      int cg = colL >> 2, cw = colL & 3;
#pragma unroll
      for (int t = 0; t < 2; t++)
#pragma unroll
        for (int r = 0; r < 4; r++) {
          int row = t * 16 + q * 4 + r;
          SF[row * 64 + (((cg ^ row) & 15) << 2) + cw] = acc4[t][n2][r];
        }
    }
    WAVE_FENCE();
    // gather row strips: lane -> (row_local = 4i + lane>>4, 4 cols at c4)
    int c4 = c * 4;
    int colG = g4 * 64 + c4;
#pragma unroll
    for (int i = 0; i < 8; i++) {
      int rowL = 4 * i + (lane >> 4);
      f32x4 v = *reinterpret_cast<const f32x4*>(&SF[rowL * 64 + ((((c4 >> 2) ^ rowL) & 15) << 2)]);
      float4 e = *reinterpret_cast<const float4*>(emb + offE[i] + colG);
      float mm = mul[i];
      float4 res;
      res.x = fmaf(v[0], mm, e.x);
      res.y = fmaf(v[1], mm, e.y);
      res.z = fmaf(v[2], mm, e.z);
      res.w = fmaf(v[3], mm, e.w);
      *reinterpret_cast<float4*>(out + (rowBase + rowL) * 512 + colG) = res;
    }
    WAVE_FENCE();
  }
}

extern "C" void kernel_launch(void* const* d_in, const int* in_sizes, int n_in,
                              void* d_out, int out_size, void* d_ws, size_t ws_size,
                              hipStream_t stream) {
  const float* jinfo = (const float*)d_in[0];
  const int*   jtok  = (const int*)d_in[1];
  const float* emb   = (const float*)d_in[2];
  const float* W1    = (const float*)d_in[3];
  const float* b1    = (const float*)d_in[4];
  const float* W2    = (const float*)d_in[5];
  const float* b2    = (const float*)d_in[6];
  const float* W3    = (const float*)d_in[7];
  const float* b3    = (const float*)d_in[8];
  const float* W4    = (const float*)d_in[9];
  float* out = (float*)d_out;
  short* ws  = (short*)d_ws;

  int rows = in_sizes[0] / 4;          // 262144
  embed_prep<<<64, 256, 0, stream>>>(W2, W3, W4, ws);
  embed_main<<<rows / 128, 256, 0, stream>>>(jinfo, jtok, emb, W1, b1, b2, b3, ws, out);
}